// Round 2
// baseline (130.293 us; speedup 1.0000x reference)
//
#include <hip/hip_runtime.h>
#include <hip/hip_fp16.h>

#define NP    128   // planets per batch
#define NH    64    // hidden dim
#define ITERS 4     // batches per wave (must be even: 2-stage software pipeline)
#define WPB   4     // waves per block

typedef __attribute__((ext_vector_type(8))) _Float16 f16x8;   // K32 MFMA A/B operand
typedef __attribute__((ext_vector_type(4))) _Float16 f16x4;   // K16 MFMA A/B operand
typedef __attribute__((ext_vector_type(2))) __fp16  hf16x2;   // cvt_pkrtz return type
typedef __attribute__((ext_vector_type(4))) float f32x4;

union FragK16 { f16x4 v; unsigned int u[2]; };
union FragK32 { f16x8 v; unsigned int u[4]; };

__device__ __forceinline__ unsigned int pack_pkrtz(float a, float b) {
    hf16x2 t = __builtin_amdgcn_cvt_pkrtz(a, b);
    return __builtin_bit_cast(unsigned int, t);
}

// packed f16 relu (v_pk_max_f16). relu(rtz(x)) == rtz(relu(x)).
__device__ __forceinline__ unsigned int relu2_pk(unsigned int u) {
    hf16x2 h = __builtin_bit_cast(hf16x2, u);
    h = __builtin_elementwise_max(h, (hf16x2)(__fp16)0.f);
    return __builtin_bit_cast(unsigned int, h);
}

// 4 independent waves/block, ITERS batches each, fully register-resident, NO LDS.
//
// R1 counters: MfmaUtil 53 / VALUBusy 51 / Occupancy 33% — ~half the cycles
// have NEITHER pipe issuing. The stall is the batch boundary: 9 global loads
// (8x pxy dwordx2 + ast) issued with their first use immediately after, ~900cy
// HBM latency exposed at every batch with only ~2.7 waves/SIMD to cover it.
//
// THIS VERSION: 2-stage software pipeline over the batch loop. Two register
// sets (pxA/axA, pxB/axB) ping-pong: batch b+1's loads are issued BEFORE batch
// b's compute, so the compiler's s_waitcnt for set B lands after ~1.5K cycles
// of MFMA/VALU work on set A. +18 VGPR; no LDS, no barriers.
//
// Layer structure (unchanged from R1):
//   layer1 16x16x16 (b1 folded as constant-1 feature), h packed to f16 in regs;
//   sigma-permutation sigma(32kk+8q+j)=16*(2kk+(j>>2))+4q+(j&3) makes the K32
//   layer2 A-operand a pure register concat of layer1 C-fragments;
//   layer2 operand roles put PLANETS on the (q,reg) axis so the relu'd msg
//   tile packed to f16 is directly a 16x16x16 B-frag, and the 128-planet
//   reduction is 8 accumulating MFMAs against an all-ones A (no LDS epilogue).
__global__ void __launch_bounds__(256, 2) gnn_wave(
    const float* __restrict__ planet_xy,  // [B][P][2]
    const float* __restrict__ planet_m,   // [P]
    const float* __restrict__ ast_xy,     // [B][2]
    const float* __restrict__ W1,         // [4][64]
    const float* __restrict__ b1,         // [64]
    const float* __restrict__ W2,         // [64][64]
    const float* __restrict__ b2,         // [64]
    float* __restrict__ out)              // [B][64]
{
    const int tid  = threadIdx.x;
    const int wv   = tid >> 6;
    const int lane = tid & 63;
    const int q    = lane >> 4;
    const int lm   = lane & 15;
    const bool q0  = (q == 0);
    const bool q1  = (q == 1);

    // ---- layer1 A-frags (16x16x16), b1 folded as constant-1 feature k=4 ----
    // A[m=16mt+lm][k=4q+j]: k<4 -> W1[k][m]; k==4 -> b1[m]; else 0.
    FragK16 w1f[4];
    #pragma unroll
    for (int mt = 0; mt < 4; mt++) {
        const int m = 16 * mt + lm;
        float wa = W1[0 * NH + m], wb = W1[1 * NH + m];
        float wc = W1[2 * NH + m], wd = W1[3 * NH + m];
        float be = b1[m];
        w1f[mt].u[0] = q0 ? pack_pkrtz(wa, wb) : (q1 ? pack_pkrtz(be, 0.f) : 0u);
        w1f[mt].u[1] = q0 ? pack_pkrtz(wc, wd) : 0u;
    }

    // ---- layer2 B-frags (16x16x32), sigma-permuted W2 rows ----
    // B[k=32kk+8q+j][n'=16np+lm] = W2[sigma(k)][n']
    FragK32 w2b[4][2];   // [np][kk]
    #pragma unroll
    for (int np = 0; np < 4; np++)
        #pragma unroll
        for (int kk = 0; kk < 2; kk++) {
            const int n = 16 * np + lm;
            const int k0 = 32 * kk + 4 * q;        // j>>2 == 0 rows
            const int k1 = 32 * kk + 16 + 4 * q;   // j>>2 == 1 rows
            w2b[np][kk].u[0] = pack_pkrtz(W2[(k0 + 0) * NH + n], W2[(k0 + 1) * NH + n]);
            w2b[np][kk].u[1] = pack_pkrtz(W2[(k0 + 2) * NH + n], W2[(k0 + 3) * NH + n]);
            w2b[np][kk].u[2] = pack_pkrtz(W2[(k1 + 0) * NH + n], W2[(k1 + 1) * NH + n]);
            w2b[np][kk].u[3] = pack_pkrtz(W2[(k1 + 2) * NH + n], W2[(k1 + 3) * NH + n]);
        }

    // b2 as layer2 C-init: output rows are planets, cols n'=16np+lm -> broadcast
    f32x4 b2f[4];
    #pragma unroll
    for (int np = 0; np < 4; np++) {
        const float bv = b2[16 * np + lm];
        b2f[np] = (f32x4){bv, bv, bv, bv};
    }

    // batch-invariant planet masses (planet 16*i + lm)
    float pmv[8];
    #pragma unroll
    for (int i = 0; i < 8; i++)
        pmv[i] = planet_m[16 * i + lm];

    const unsigned int bf0_const = q1 ? pack_pkrtz(1.f, 0.f) : 0u;
    const f32x4 zf = (f32x4){0.f, 0.f, 0.f, 0.f};

    // all-ones A-frag for the planet-reduction MFMA
    FragK16 onesA;
    onesA.u[0] = 0x3C003C00u;   // (1.0h, 1.0h)
    onesA.u[1] = 0x3C003C00u;

    const int b0 = (blockIdx.x * WPB + wv) * ITERS;

    // ---- one batch: registers -> out[b][lane], fully inlined ----
    auto do_batch = [&](const float2 (&pxy)[8], float2 axy, int b)
        __attribute__((always_inline))
    {
        f32x4 redD[4];
        #pragma unroll
        for (int np = 0; np < 4; np++)
            redD[np] = zf;

        #pragma unroll
        for (int mi = 0; mi < 8; ++mi) {
            // feats B-frag for planets 16mi..16mi+15
            float dx = pxy[mi].x - axy.x, dy = pxy[mi].y - axy.y;
            float inv = __builtin_amdgcn_rsqf(fmaf(dx, dx, fmaf(dy, dy, 1e-6f)));
            FragK16 bf;
            bf.u[0] = q0 ? pack_pkrtz(dx, dy)        : bf0_const;
            bf.u[1] = q0 ? pack_pkrtz(inv, pmv[mi])  : 0u;

            // layer1: hT fragments straight into registers (K16 C layout)
            FragK16 hb[4];
            #pragma unroll
            for (int mt = 0; mt < 4; mt++) {
                f32x4 c = __builtin_amdgcn_mfma_f32_16x16x16f16(w1f[mt].v, bf.v, zf, 0, 0, 0);
                hb[mt].u[0] = relu2_pk(pack_pkrtz(c[0], c[1]));
                hb[mt].u[1] = relu2_pk(pack_pkrtz(c[2], c[3]));
            }

            // sigma-ordered K32 A-frags: pure register concatenation
            FragK32 hA[2];
            #pragma unroll
            for (int kk = 0; kk < 2; kk++) {
                hA[kk].u[0] = hb[2 * kk + 0].u[0];
                hA[kk].u[1] = hb[2 * kk + 0].u[1];
                hA[kk].u[2] = hb[2 * kk + 1].u[0];
                hA[kk].u[3] = hb[2 * kk + 1].u[1];
            }

            // layer2: msg tile [p=4q+r][n'=16np+lm], full-rate K32
            #pragma unroll
            for (int np = 0; np < 4; np++) {
                f32x4 acc = __builtin_amdgcn_mfma_f32_16x16x32_f16(hA[0].v, w2b[np][0].v, b2f[np], 0, 0, 0);
                acc = __builtin_amdgcn_mfma_f32_16x16x32_f16(hA[1].v, w2b[np][1].v, acc, 0, 0, 0);

                // relu + pack to fp16: directly a 16x16x16 B-frag
                FragK16 mf;
                mf.u[0] = relu2_pk(pack_pkrtz(acc[0], acc[1]));
                mf.u[1] = relu2_pk(pack_pkrtz(acc[2], acc[3]));

                // planet reduction on the MFMA pipe: redD += ones @ mf
                redD[np] = __builtin_amdgcn_mfma_f32_16x16x16f16(onesA.v, mf.v, redD[np], 0, 0, 0);
            }
        }

        // lane 16q+lm needs n' = lane -> select np == q; coalesced b32 store
        float v = q0 ? redD[0][0]
                : q1 ? redD[1][0]
                : (q == 2) ? redD[2][0] : redD[3][0];
        out[(size_t)b * NH + lane] = v;
    };

    // ---- 2-stage software pipeline over batches ----
    float2 pxA[8], pxB[8];
    float2 axA, axB;

    axA = *(const float2*)&ast_xy[2 * b0];
    #pragma unroll
    for (int i = 0; i < 8; i++)
        pxA[i] = *(const float2*)&planet_xy[((size_t)b0 * NP + 16 * i + lm) * 2];

    #pragma unroll
    for (int it = 0; it < ITERS; it += 2) {
        const int b = b0 + it;

        // prefetch batch b+1 into set B (latency hides under compute of b)
        axB = *(const float2*)&ast_xy[2 * (b + 1)];
        #pragma unroll
        for (int i = 0; i < 8; i++)
            pxB[i] = *(const float2*)&planet_xy[((size_t)(b + 1) * NP + 16 * i + lm) * 2];

        do_batch(pxA, axA, b);

        // prefetch batch b+2 into set A (hides under compute of b+1)
        if (it + 2 < ITERS) {
            axA = *(const float2*)&ast_xy[2 * (b + 2)];
            #pragma unroll
            for (int i = 0; i < 8; i++)
                pxA[i] = *(const float2*)&planet_xy[((size_t)(b + 2) * NP + 16 * i + lm) * 2];
        }

        do_batch(pxB, axB, b + 1);
    }
}

extern "C" void kernel_launch(void* const* d_in, const int* in_sizes, int n_in,
                              void* d_out, int out_size, void* d_ws, size_t ws_size,
                              hipStream_t stream) {
    const float* planet_xy = (const float*)d_in[0];
    const float* planet_m  = (const float*)d_in[1];
    const float* ast_xy    = (const float*)d_in[2];
    const float* W1        = (const float*)d_in[3];
    const float* b1        = (const float*)d_in[4];
    const float* W2        = (const float*)d_in[5];
    const float* b2        = (const float*)d_in[6];
    float* outp            = (float*)d_out;

    const int B = in_sizes[2] / 2;   // ast_xy is [B][2]
    const int batches_per_block = WPB * ITERS;
    const int grid = (B + batches_per_block - 1) / batches_per_block;

    gnn_wave<<<grid, 256, 0, stream>>>(planet_xy, planet_m, ast_xy, W1, b1, W2, b2, outp);
}

// Round 3
// 128.165 us; speedup vs baseline: 1.0166x; 1.0166x over previous
//
#include <hip/hip_runtime.h>
#include <hip/hip_fp16.h>

#define NP    128   // planets per batch
#define NH    64    // hidden dim
#define ITERS 8     // batches per wave
#define WPB   4     // waves per block

typedef __attribute__((ext_vector_type(8))) _Float16 f16x8;   // K32 MFMA A/B operand
typedef __attribute__((ext_vector_type(4))) _Float16 f16x4;   // K16 MFMA A/B operand
typedef __attribute__((ext_vector_type(2))) __fp16  hf16x2;   // cvt_pkrtz return type
typedef __attribute__((ext_vector_type(4))) float f32x4;

union FragK16 { f16x4 v; unsigned int u[2]; };
union FragK32 { f16x8 v; unsigned int u[4]; };

__device__ __forceinline__ unsigned int pack_pkrtz(float a, float b) {
    hf16x2 t = __builtin_amdgcn_cvt_pkrtz(a, b);
    return __builtin_bit_cast(unsigned int, t);
}

// packed f16 relu (v_pk_max_f16). relu(rtz(x)) == rtz(relu(x)).
__device__ __forceinline__ unsigned int relu2_pk(unsigned int u) {
    hf16x2 h = __builtin_bit_cast(hf16x2, u);
    h = __builtin_elementwise_max(h, (hf16x2)(__fp16)0.f);
    return __builtin_bit_cast(unsigned int, h);
}

// 4 independent waves/block, ITERS batches each, fully register-resident, NO LDS.
//
// R2 LESSON: VGPR 60->72 crossed a wave-residency tier (m69: waves halve at
// vgpr=64) and regressed 52.6->63us. All changes here are register-neutral:
//  * in-place rotating prefetch: pxy[mi] is reloaded with NEXT batch's data
//    right after its last use (same registers, +2 for ast double-buffer) —
//    next batch's HBM latency hides under the remaining ~1000cy of compute.
//  * layer1 epilogue writes straight into the K32 hA slots (no hb middleman).
//  * planet masses packed to f16 pairs: 8 regs -> 4, +1 VALU/mi.
//  * ITERS 8 (grid 1024 = 4 blocks/CU exactly) halves setup amortization;
//    batch loop pinned rolled so the compiler can't inflate registers.
//
// Layer structure (unchanged from R1):
//   layer1 16x16x16 (b1 folded as constant-1 feature), h packed to f16 in regs;
//   sigma-permutation sigma(32kk+8q+j)=16*(2kk+(j>>2))+4q+(j&3) makes the K32
//   layer2 A-operand a pure register concat of layer1 C-fragments;
//   layer2 operand roles put PLANETS on the (q,reg) axis so the relu'd msg
//   tile packed to f16 is directly a 16x16x16 B-frag, and the 128-planet
//   reduction is 8 accumulating MFMAs against an all-ones A (no LDS epilogue).
__global__ void __launch_bounds__(256, 2) gnn_wave(
    const float* __restrict__ planet_xy,  // [B][P][2]
    const float* __restrict__ planet_m,   // [P]
    const float* __restrict__ ast_xy,     // [B][2]
    const float* __restrict__ W1,         // [4][64]
    const float* __restrict__ b1,         // [64]
    const float* __restrict__ W2,         // [64][64]
    const float* __restrict__ b2,         // [64]
    float* __restrict__ out,              // [B][64]
    int Btot)
{
    const int tid  = threadIdx.x;
    const int wv   = tid >> 6;
    const int lane = tid & 63;
    const int q    = lane >> 4;
    const int lm   = lane & 15;
    const bool q0  = (q == 0);
    const bool q1  = (q == 1);

    // ---- layer1 A-frags (16x16x16), b1 folded as constant-1 feature k=4 ----
    // A[m=16mt+lm][k=4q+j]: k<4 -> W1[k][m]; k==4 -> b1[m]; else 0.
    FragK16 w1f[4];
    #pragma unroll
    for (int mt = 0; mt < 4; mt++) {
        const int m = 16 * mt + lm;
        float wa = W1[0 * NH + m], wb = W1[1 * NH + m];
        float wc = W1[2 * NH + m], wd = W1[3 * NH + m];
        float be = b1[m];
        w1f[mt].u[0] = q0 ? pack_pkrtz(wa, wb) : (q1 ? pack_pkrtz(be, 0.f) : 0u);
        w1f[mt].u[1] = q0 ? pack_pkrtz(wc, wd) : 0u;
    }

    // ---- layer2 B-frags (16x16x32), sigma-permuted W2 rows ----
    // B[k=32kk+8q+j][n'=16np+lm] = W2[sigma(k)][n']
    FragK32 w2b[4][2];   // [np][kk]
    #pragma unroll
    for (int np = 0; np < 4; np++)
        #pragma unroll
        for (int kk = 0; kk < 2; kk++) {
            const int n = 16 * np + lm;
            const int k0 = 32 * kk + 4 * q;        // j>>2 == 0 rows
            const int k1 = 32 * kk + 16 + 4 * q;   // j>>2 == 1 rows
            w2b[np][kk].u[0] = pack_pkrtz(W2[(k0 + 0) * NH + n], W2[(k0 + 1) * NH + n]);
            w2b[np][kk].u[1] = pack_pkrtz(W2[(k0 + 2) * NH + n], W2[(k0 + 3) * NH + n]);
            w2b[np][kk].u[2] = pack_pkrtz(W2[(k1 + 0) * NH + n], W2[(k1 + 1) * NH + n]);
            w2b[np][kk].u[3] = pack_pkrtz(W2[(k1 + 2) * NH + n], W2[(k1 + 3) * NH + n]);
        }

    // b2 as layer2 C-init: output rows are planets, cols n'=16np+lm -> broadcast
    f32x4 b2f[4];
    #pragma unroll
    for (int np = 0; np < 4; np++) {
        const float bv = b2[16 * np + lm];
        b2f[np] = (f32x4){bv, bv, bv, bv};
    }

    // planet masses as f16 pairs: pmh[i] = (m[32i+lm] lo, m[32i+16+lm] hi)
    // even mi=2i -> lo half, odd mi=2i+1 -> hi half. (same f16 rounding as R1)
    unsigned int pmh[4];
    #pragma unroll
    for (int i = 0; i < 4; i++)
        pmh[i] = pack_pkrtz(planet_m[32 * i + lm], planet_m[32 * i + 16 + lm]);

    const unsigned int bf0_const = q1 ? pack_pkrtz(1.f, 0.f) : 0u;
    const f32x4 zf = (f32x4){0.f, 0.f, 0.f, 0.f};

    // all-ones A-frag for the planet-reduction MFMA
    FragK16 onesA;
    onesA.u[0] = 0x3C003C00u;   // (1.0h, 1.0h)
    onesA.u[1] = 0x3C003C00u;

    int b = (blockIdx.x * WPB + wv) * ITERS;

    // ---- preload batch b ----
    float2 axy = *(const float2*)&ast_xy[2 * b];
    float2 pxy[8];
    #pragma unroll
    for (int i = 0; i < 8; i++)
        pxy[i] = *(const float2*)&planet_xy[((size_t)b * NP + 16 * i + lm) * 2];

    #pragma unroll 1
    for (int it = 0; it < ITERS; ++it, ++b) {
        // next batch index (clamped: last batch harmlessly re-prefetches itself)
        const int bn = (b + 1 < Btot) ? b + 1 : b;
        // prefetch next asteroid early (+2 regs)
        const float2 axN = *(const float2*)&ast_xy[2 * bn];

        f32x4 redD[4];
        #pragma unroll
        for (int np = 0; np < 4; np++)
            redD[np] = zf;

        #pragma unroll
        for (int mi = 0; mi < 8; ++mi) {
            // last use of pxy[mi] for this batch, then IN-PLACE prefetch of
            // next batch's group — same registers, latency hides under the
            // remaining (7-mi)/8 of this batch's compute.
            const float2 p = pxy[mi];
            pxy[mi] = *(const float2*)&planet_xy[((size_t)bn * NP + 16 * mi + lm) * 2];

            // feats B-frag for planets 16mi..16mi+15
            float dx = p.x - axy.x, dy = p.y - axy.y;
            float inv = __builtin_amdgcn_rsqf(fmaf(dx, dx, fmaf(dy, dy, 1e-6f)));
            unsigned int invp = pack_pkrtz(inv, 0.f);            // [inv, 0]
            unsigned int pmsel = (mi & 1)
                ? ((pmh[mi >> 1] & 0xFFFF0000u) | invp)          // [inv, m_odd]
                : ((pmh[mi >> 1] << 16) | invp);                 // [inv, m_even]
            FragK16 bf;
            bf.u[0] = q0 ? pack_pkrtz(dx, dy) : bf0_const;
            bf.u[1] = q0 ? pmsel : 0u;

            // layer1: relu'd h packs written DIRECTLY into sigma-ordered K32
            // A-frag slots: hA[mt>>1].u[2*(mt&1)+{0,1}]
            FragK32 hA[2];
            #pragma unroll
            for (int mt = 0; mt < 4; mt++) {
                f32x4 c = __builtin_amdgcn_mfma_f32_16x16x16f16(w1f[mt].v, bf.v, zf, 0, 0, 0);
                hA[mt >> 1].u[2 * (mt & 1) + 0] = relu2_pk(pack_pkrtz(c[0], c[1]));
                hA[mt >> 1].u[2 * (mt & 1) + 1] = relu2_pk(pack_pkrtz(c[2], c[3]));
            }

            // layer2: msg tile [p=4q+r][n'=16np+lm], full-rate K32
            #pragma unroll
            for (int np = 0; np < 4; np++) {
                f32x4 acc = __builtin_amdgcn_mfma_f32_16x16x32_f16(hA[0].v, w2b[np][0].v, b2f[np], 0, 0, 0);
                acc = __builtin_amdgcn_mfma_f32_16x16x32_f16(hA[1].v, w2b[np][1].v, acc, 0, 0, 0);

                // relu + pack to fp16: directly a 16x16x16 B-frag
                FragK16 mf;
                mf.u[0] = relu2_pk(pack_pkrtz(acc[0], acc[1]));
                mf.u[1] = relu2_pk(pack_pkrtz(acc[2], acc[3]));

                // planet reduction on the MFMA pipe: redD += ones @ mf
                redD[np] = __builtin_amdgcn_mfma_f32_16x16x16f16(onesA.v, mf.v, redD[np], 0, 0, 0);
            }
        }

        // rotate asteroid double-buffer
        axy = axN;

        // lane 16q+lm needs n' = lane -> select np == q; coalesced b32 store
        float v = q0 ? redD[0][0]
                : q1 ? redD[1][0]
                : (q == 2) ? redD[2][0] : redD[3][0];
        out[(size_t)b * NH + lane] = v;
    }
}

extern "C" void kernel_launch(void* const* d_in, const int* in_sizes, int n_in,
                              void* d_out, int out_size, void* d_ws, size_t ws_size,
                              hipStream_t stream) {
    const float* planet_xy = (const float*)d_in[0];
    const float* planet_m  = (const float*)d_in[1];
    const float* ast_xy    = (const float*)d_in[2];
    const float* W1        = (const float*)d_in[3];
    const float* b1        = (const float*)d_in[4];
    const float* W2        = (const float*)d_in[5];
    const float* b2        = (const float*)d_in[6];
    float* outp            = (float*)d_out;

    const int B = in_sizes[2] / 2;   // ast_xy is [B][2]
    const int batches_per_block = WPB * ITERS;
    const int grid = (B + batches_per_block - 1) / batches_per_block;

    gnn_wave<<<grid, 256, 0, stream>>>(planet_xy, planet_m, ast_xy, W1, b1, W2, b2, outp, B);
}

// Round 5
// 123.625 us; speedup vs baseline: 1.0539x; 1.0367x over previous
//
#include <hip/hip_runtime.h>
#include <hip/hip_fp16.h>

#define NP    128   // planets per batch
#define NH    64    // hidden dim
#define ITERS 4     // batches per wave
#define WPB   4     // waves per block

typedef __attribute__((ext_vector_type(8))) _Float16 f16x8;   // K32 MFMA A/B operand
typedef __attribute__((ext_vector_type(4))) _Float16 f16x4;   // K16 MFMA A/B operand
typedef __attribute__((ext_vector_type(2))) __fp16  hf16x2;   // cvt_pkrtz return type
typedef __attribute__((ext_vector_type(4))) float f32x4;

union FragK16 { f16x4 v; unsigned int u[2]; };
union FragK32 { f16x8 v; unsigned int u[4]; };

__device__ __forceinline__ unsigned int pack_pkrtz(float a, float b) {
    hf16x2 t = __builtin_amdgcn_cvt_pkrtz(a, b);
    return __builtin_bit_cast(unsigned int, t);
}

// packed f16 relu (v_pk_max_f16). relu(rtz(x)) == rtz(relu(x)).
__device__ __forceinline__ unsigned int relu2_pk(unsigned int u) {
    hf16x2 h = __builtin_bit_cast(hf16x2, u);
    h = __builtin_elementwise_max(h, (hf16x2)(__fp16)0.f);
    return __builtin_bit_cast(unsigned int, h);
}

// 4 independent waves/block, ITERS batches each, fully register-resident, NO LDS.
//
// (Resubmission of R4 — previous bench failed on container infra, no kernel
// diagnostic; source audited for OOB/graph-capture hazards, none found.)
//
// R1 (52.6us) showed MfmaUtil+VALUBusy ~= 104% with duration ~= SUM of the two
// pipe times: the pipes ALTERNATE (strict per-wave dependence chain) instead of
// overlapping, and ~2.6 resident waves/SIMD can't cover the gaps. R2/R3 showed
// every extra ~8-12 VGPR costs a resident wave (-10..20%). This version keeps
// the R1 register budget shape and attacks the serialization directly:
//
//  * mi-SOFTWARE-PIPELINE: layer1's raw MFMA outputs c[4] are held across one
//    mi iteration. Iteration mi: pack PREVIOUS c -> hA (deps long ready),
//    issue feat+L1 for mi+1 (independent, fills the MFMA pipe's shadow),
//    then L2a x4 / L2b x4 / packs / reduce x4 for mi with all dependent
//    consumers >=90cy behind their producers.
//  * ZERO-VALU ROTATING PREFETCH (R3's idea minus its VALU tax): one per-lane
//    base pointer per batch; the reload of the dead pxy[mi] slot is a single
//    global_load_dwordx2 with compile-time offset:128*mi. Last iteration
//    self-prefetches (L2-hot) instead of stealing the next wave's batch, so
//    FETCH_SIZE does not grow. axN prefetched at mi==5.
//
// Layer structure (unchanged since R1):
//   layer1 16x16x16 (b1 folded as constant-1 feature k=4);
//   sigma(32kk+8q+j)=16*(2kk+(j>>2))+4q+(j&3) makes the K32 layer2 A-operand a
//   pure register concat of layer1 C-fragments (written directly in place);
//   layer2 puts PLANETS on the (q,reg) axis so the relu'd msg tile packed to
//   f16 is directly a 16x16x16 B-frag and the 128-planet reduction is 8
//   accumulating MFMAs against an all-ones A. No LDS, no barriers.
__global__ void __launch_bounds__(256, 2) gnn_wave(
    const float* __restrict__ planet_xy,  // [B][P][2]
    const float* __restrict__ planet_m,   // [P]
    const float* __restrict__ ast_xy,     // [B][2]
    const float* __restrict__ W1,         // [4][64]
    const float* __restrict__ b1,         // [64]
    const float* __restrict__ W2,         // [64][64]
    const float* __restrict__ b2,         // [64]
    float* __restrict__ out)              // [B][64]
{
    const int tid  = threadIdx.x;
    const int wv   = tid >> 6;
    const int lane = tid & 63;
    const int q    = lane >> 4;
    const int lm   = lane & 15;
    const bool q0  = (q == 0);
    const bool q1  = (q == 1);

    // ---- layer1 A-frags (16x16x16), b1 folded as constant-1 feature k=4 ----
    FragK16 w1f[4];
    #pragma unroll
    for (int mt = 0; mt < 4; mt++) {
        const int m = 16 * mt + lm;
        float wa = W1[0 * NH + m], wb = W1[1 * NH + m];
        float wc = W1[2 * NH + m], wd = W1[3 * NH + m];
        float be = b1[m];
        w1f[mt].u[0] = q0 ? pack_pkrtz(wa, wb) : (q1 ? pack_pkrtz(be, 0.f) : 0u);
        w1f[mt].u[1] = q0 ? pack_pkrtz(wc, wd) : 0u;
    }

    // ---- layer2 B-frags (16x16x32), sigma-permuted W2 rows ----
    FragK32 w2b[4][2];   // [np][kk]
    #pragma unroll
    for (int np = 0; np < 4; np++)
        #pragma unroll
        for (int kk = 0; kk < 2; kk++) {
            const int n = 16 * np + lm;
            const int k0 = 32 * kk + 4 * q;        // j>>2 == 0 rows
            const int k1 = 32 * kk + 16 + 4 * q;   // j>>2 == 1 rows
            w2b[np][kk].u[0] = pack_pkrtz(W2[(k0 + 0) * NH + n], W2[(k0 + 1) * NH + n]);
            w2b[np][kk].u[1] = pack_pkrtz(W2[(k0 + 2) * NH + n], W2[(k0 + 3) * NH + n]);
            w2b[np][kk].u[2] = pack_pkrtz(W2[(k1 + 0) * NH + n], W2[(k1 + 1) * NH + n]);
            w2b[np][kk].u[3] = pack_pkrtz(W2[(k1 + 2) * NH + n], W2[(k1 + 3) * NH + n]);
        }

    // b2 as layer2 C-init: output rows are planets, cols n'=16np+lm -> broadcast
    f32x4 b2f[4];
    #pragma unroll
    for (int np = 0; np < 4; np++) {
        const float bv = b2[16 * np + lm];
        b2f[np] = (f32x4){bv, bv, bv, bv};
    }

    // batch-invariant planet masses (planet 16*i + lm)
    float pmv[8];
    #pragma unroll
    for (int i = 0; i < 8; i++)
        pmv[i] = planet_m[16 * i + lm];

    const unsigned int bf0_const = q1 ? pack_pkrtz(1.f, 0.f) : 0u;
    const f32x4 zf = (f32x4){0.f, 0.f, 0.f, 0.f};

    // all-ones A-frag for the planet-reduction MFMA
    FragK16 onesA;
    onesA.u[0] = 0x3C003C00u;   // (1.0h, 1.0h)
    onesA.u[1] = 0x3C003C00u;

    int b = (blockIdx.x * WPB + wv) * ITERS;

    // ---- preload batch b ----
    float2 axy = *(const float2*)&ast_xy[2 * b];
    float2 pxy[8];
    #pragma unroll
    for (int i = 0; i < 8; i++)
        pxy[i] = *(const float2*)&planet_xy[((size_t)b * NP + 16 * i + lm) * 2];

    #pragma unroll 1
    for (int it = 0; it < ITERS; ++it, ++b) {
        // next batch this WAVE will run; on the last iteration self-prefetch
        // (L2-hot, free) instead of stealing the next wave's cold batch.
        const int bn = (it + 1 < ITERS) ? b + 1 : b;
        // single per-lane base pointer; per-mi reload is then ONE dwordx2 with
        // compile-time imm offset (128*mi bytes) — zero per-mi address VALU.
        const float* pnext = planet_xy + ((size_t)bn * NP + lm) * 2;

        float2 axN = axy;   // overwritten by the mi==5 prefetch

        f32x4 redD[4];
        #pragma unroll
        for (int np = 0; np < 4; np++)
            redD[np] = zf;

        // ---- pipeline prologue: feature + L1 for mi=0 ----
        f32x4 c[4];
        {
            float dx = pxy[0].x - axy.x, dy = pxy[0].y - axy.y;
            float inv = __builtin_amdgcn_rsqf(fmaf(dx, dx, fmaf(dy, dy, 1e-6f)));
            FragK16 bf;
            bf.u[0] = q0 ? pack_pkrtz(dx, dy)       : bf0_const;
            bf.u[1] = q0 ? pack_pkrtz(inv, pmv[0])  : 0u;
            #pragma unroll
            for (int mt = 0; mt < 4; mt++)
                c[mt] = __builtin_amdgcn_mfma_f32_16x16x16f16(w1f[mt].v, bf.v, zf, 0, 0, 0);
        }

        #pragma unroll
        for (int mi = 0; mi < 8; ++mi) {
            // (1) pack PREVIOUS iteration's layer1 output into sigma-ordered
            //     K32 A-frags — producers are >=1 iteration old.
            FragK32 hA[2];
            #pragma unroll
            for (int mt = 0; mt < 4; mt++) {
                hA[mt >> 1].u[2 * (mt & 1) + 0] = relu2_pk(pack_pkrtz(c[mt][0], c[mt][1]));
                hA[mt >> 1].u[2 * (mt & 1) + 1] = relu2_pk(pack_pkrtz(c[mt][2], c[mt][3]));
            }

            // (2) issue feature + L1 for mi+1 (independent of everything below;
            //     executes in the shadow of mi's layer2 stream)
            if (mi < 7) {
                float dx = pxy[mi + 1].x - axy.x, dy = pxy[mi + 1].y - axy.y;
                float inv = __builtin_amdgcn_rsqf(fmaf(dx, dx, fmaf(dy, dy, 1e-6f)));
                FragK16 bf;
                bf.u[0] = q0 ? pack_pkrtz(dx, dy)            : bf0_const;
                bf.u[1] = q0 ? pack_pkrtz(inv, pmv[mi + 1])  : 0u;
                #pragma unroll
                for (int mt = 0; mt < 4; mt++)
                    c[mt] = __builtin_amdgcn_mfma_f32_16x16x16f16(w1f[mt].v, bf.v, zf, 0, 0, 0);
            }

            // (3) rotating prefetch: pxy[mi] is dead (its feature ran at mi-1 /
            //     prologue) — reload it with NEXT batch's group mi.
            pxy[mi] = *(const float2*)(pnext + 32 * mi);
            if (mi == 5)
                axN = *(const float2*)&ast_xy[2 * bn];

            // (4) layer2, breadth-first: 4 independent L2a, then 4 L2b (each
            //     >=4 MFMAs behind its producer), then packs, then reduces.
            f32x4 acc[4];
            #pragma unroll
            for (int np = 0; np < 4; np++)
                acc[np] = __builtin_amdgcn_mfma_f32_16x16x32_f16(hA[0].v, w2b[np][0].v, b2f[np], 0, 0, 0);
            #pragma unroll
            for (int np = 0; np < 4; np++)
                acc[np] = __builtin_amdgcn_mfma_f32_16x16x32_f16(hA[1].v, w2b[np][1].v, acc[np], 0, 0, 0);

            FragK16 mf[4];
            #pragma unroll
            for (int np = 0; np < 4; np++) {
                mf[np].u[0] = relu2_pk(pack_pkrtz(acc[np][0], acc[np][1]));
                mf[np].u[1] = relu2_pk(pack_pkrtz(acc[np][2], acc[np][3]));
            }
            #pragma unroll
            for (int np = 0; np < 4; np++)
                redD[np] = __builtin_amdgcn_mfma_f32_16x16x16f16(onesA.v, mf[np].v, redD[np], 0, 0, 0);
        }

        // rotate asteroid for the next batch
        axy = axN;

        // lane 16q+lm needs n' = lane -> select np == q; coalesced b32 store
        float v = q0 ? redD[0][0]
                : q1 ? redD[1][0]
                : (q == 2) ? redD[2][0] : redD[3][0];
        out[(size_t)b * NH + lane] = v;
    }
}

extern "C" void kernel_launch(void* const* d_in, const int* in_sizes, int n_in,
                              void* d_out, int out_size, void* d_ws, size_t ws_size,
                              hipStream_t stream) {
    const float* planet_xy = (const float*)d_in[0];
    const float* planet_m  = (const float*)d_in[1];
    const float* ast_xy    = (const float*)d_in[2];
    const float* W1        = (const float*)d_in[3];
    const float* b1        = (const float*)d_in[4];
    const float* W2        = (const float*)d_in[5];
    const float* b2        = (const float*)d_in[6];
    float* outp            = (float*)d_out;

    const int B = in_sizes[2] / 2;   // ast_xy is [B][2]
    const int batches_per_block = WPB * ITERS;
    const int grid = (B + batches_per_block - 1) / batches_per_block;

    gnn_wave<<<grid, 256, 0, stream>>>(planet_xy, planet_m, ast_xy, W1, b1, W2, b2, outp);
}